// Round 2
// baseline (106.707 us; speedup 1.0000x reference)
//
#include <hip/hip_runtime.h>
#include <hip/hip_bf16.h>

typedef __bf16 bf16x8 __attribute__((ext_vector_type(8)));
typedef float  f32x4  __attribute__((ext_vector_type(4)));

#define LDP 72  // padded LDS row stride in bf16 elems (144B): breaks 128B-stride bank conflicts, keeps 16B align

// ---------------- Kernel 1: fused QKV projection GEMM ----------------
// y[m, c] = sum_e x[m,e] * Wc[c,e];  c in [0,192): 0-63 -> k (Wk), 64-127 -> q (Wq), 128-191 -> v (Wv)
// Outputs: kbuf[m][64], qbuf[m][64] bf16 row-major; vtbuf[b][h][t] bf16 (V transposed per batch).
__global__ __launch_bounds__(512) void proj_kernel(
    const float* __restrict__ x, const float* __restrict__ Wk,
    const float* __restrict__ Wq, const float* __restrict__ Wv,
    __bf16* __restrict__ kbuf, __bf16* __restrict__ qbuf, __bf16* __restrict__ vtbuf)
{
    __shared__ __align__(16) __bf16 Alds[64 * LDP];    // x tile 64 rows x 64 k
    __shared__ __align__(16) __bf16 Wlds[192 * LDP];   // W tile 192 rows x 64 k
    __shared__ __align__(16) __bf16 Vtl[64 * LDP];     // v transpose buffer (h x t_rel)

    const int tid  = threadIdx.x;
    const int lane = tid & 63;
    const int wid  = tid >> 6;     // 0..7
    const int wm   = wid >> 2;     // 0..1 : M half (32 rows)
    const int wn   = wid & 3;      // 0..3 : N quarter (48 cols)
    const int mbase = blockIdx.x * 64;

    const int cl = lane & 15;          // fragment row/col lane index
    const int e0 = (lane >> 4) * 8;    // k-offset within 32-chunk
    const int r0 = (lane >> 4) * 4;    // C/D row group

    const int srow = tid >> 3;         // staging row 0..63
    const int scg  = tid & 7;          // staging 16B chunk 0..7

    f32x4 acc[2][3];
    #pragma unroll
    for (int i = 0; i < 2; i++)
        #pragma unroll
        for (int j = 0; j < 3; j++) acc[i][j] = (f32x4){0.f, 0.f, 0.f, 0.f};

    for (int kb = 0; kb < 1024; kb += 64) {
        // stage A: 64x64 fp32 -> bf16
        {
            const float* src = x + (size_t)(mbase + srow) * 1024 + kb + scg * 8;
            float4 f0 = *reinterpret_cast<const float4*>(src);
            float4 f1 = *reinterpret_cast<const float4*>(src + 4);
            bf16x8 v;
            v[0] = (__bf16)f0.x; v[1] = (__bf16)f0.y; v[2] = (__bf16)f0.z; v[3] = (__bf16)f0.w;
            v[4] = (__bf16)f1.x; v[5] = (__bf16)f1.y; v[6] = (__bf16)f1.z; v[7] = (__bf16)f1.w;
            *reinterpret_cast<bf16x8*>(&Alds[srow * LDP + scg * 8]) = v;
        }
        // stage W: 3 passes (Wk, Wq, Wv), 64 rows each
        #pragma unroll
        for (int p = 0; p < 3; p++) {
            const float* wp = (p == 0) ? Wk : (p == 1) ? Wq : Wv;
            const float* src = wp + (size_t)srow * 1024 + kb + scg * 8;
            float4 f0 = *reinterpret_cast<const float4*>(src);
            float4 f1 = *reinterpret_cast<const float4*>(src + 4);
            bf16x8 v;
            v[0] = (__bf16)f0.x; v[1] = (__bf16)f0.y; v[2] = (__bf16)f0.z; v[3] = (__bf16)f0.w;
            v[4] = (__bf16)f1.x; v[5] = (__bf16)f1.y; v[6] = (__bf16)f1.z; v[7] = (__bf16)f1.w;
            *reinterpret_cast<bf16x8*>(&Wlds[(p * 64 + srow) * LDP + scg * 8]) = v;
        }
        __syncthreads();
        #pragma unroll
        for (int kk = 0; kk < 2; kk++) {
            bf16x8 a[2], bb[3];
            #pragma unroll
            for (int mf = 0; mf < 2; mf++)
                a[mf] = *reinterpret_cast<const bf16x8*>(&Alds[(wm * 32 + mf * 16 + cl) * LDP + kk * 32 + e0]);
            #pragma unroll
            for (int nf = 0; nf < 3; nf++)
                bb[nf] = *reinterpret_cast<const bf16x8*>(&Wlds[(wn * 48 + nf * 16 + cl) * LDP + kk * 32 + e0]);
            #pragma unroll
            for (int mf = 0; mf < 2; mf++)
                #pragma unroll
                for (int nf = 0; nf < 3; nf++)
                    acc[mf][nf] = __builtin_amdgcn_mfma_f32_16x16x32_bf16(a[mf], bb[nf], acc[mf][nf], 0, 0, 0);
        }
        __syncthreads();
    }

    // epilogue: k,q direct bf16 stores; v -> LDS transpose -> vtbuf
    #pragma unroll
    for (int mf = 0; mf < 2; mf++)
        #pragma unroll
        for (int nf = 0; nf < 3; nf++) {
            int c = wn * 48 + nf * 16 + cl;
            #pragma unroll
            for (int r = 0; r < 4; r++) {
                int mrel = wm * 32 + mf * 16 + r0 + r;
                float v = acc[mf][nf][r];
                if (c < 64)        kbuf[(size_t)(mbase + mrel) * 64 + c]         = (__bf16)v;
                else if (c < 128)  qbuf[(size_t)(mbase + mrel) * 64 + (c - 64)]  = (__bf16)v;
                else               Vtl[(c - 128) * LDP + mrel]                   = (__bf16)v;
            }
        }
    __syncthreads();
    {
        int b   = mbase >> 11;       // 2048 rows per batch
        int tof = mbase & 2047;
        bf16x8 v8 = *reinterpret_cast<const bf16x8*>(&Vtl[srow * LDP + scg * 8]);
        *reinterpret_cast<bf16x8*>(&vtbuf[(size_t)b * 64 * 2048 + (size_t)srow * 2048 + tof + scg * 8]) = v8;
    }
}

// ---------------- Kernel 2: flash attention with causal + padding mask ----------------
// grid (32 q-tiles, 8 batches), 256 threads = 4 waves; wave w owns 16 q rows.
// Padding mask is an OUTER PRODUCT mask[q]*mask[k]: rows with mask[q]==0 are fully
// masked -> softmax NaN -> nan_to_num -> 0 in the reference. We apply the column
// mask inside the loop and the ROW mask at the epilogue (exact: output = 0).
__global__ __launch_bounds__(256) void attn_kernel(
    const __bf16* __restrict__ qbuf, const __bf16* __restrict__ kbuf,
    const __bf16* __restrict__ vtbuf, const int* __restrict__ mask,
    float* __restrict__ out)
{
    __shared__ __align__(16) __bf16 Klds[64 * LDP];     // kv rows x 64 h
    __shared__ __align__(16) __bf16 Vlds[64 * LDP];     // h rows x 64 kv  (from vtbuf)
    __shared__ __align__(16) __bf16 Plds[4][16 * LDP];  // per-wave P tile: 16 q x 64 kv

    const int tid  = threadIdx.x;
    const int lane = tid & 63;
    const int w    = tid >> 6;
    const int qt   = blockIdx.x;
    const int b    = blockIdx.y;
    const int qbase = qt * 64 + w * 16;

    const int cl = lane & 15;
    const int e0 = (lane >> 4) * 8;
    const int r0 = (lane >> 4) * 4;

    // Q fragments held in registers for the whole kernel
    bf16x8 aq[2];
    #pragma unroll
    for (int kk = 0; kk < 2; kk++)
        aq[kk] = *reinterpret_cast<const bf16x8*>(&qbuf[((size_t)b * 2048 + qbase + cl) * 64 + kk * 32 + e0]);

    float ms[4], ls[4];
    f32x4 acc[4];
    #pragma unroll
    for (int r = 0; r < 4; r++) { ms[r] = -INFINITY; ls[r] = 0.f; }
    #pragma unroll
    for (int hf = 0; hf < 4; hf++) acc[hf] = (f32x4){0.f, 0.f, 0.f, 0.f};

    const int srow = tid >> 3;   // 0..31
    const int scg  = tid & 7;

    for (int j = 0; j <= qt; j++) {
        // stage K tile (kv-major) and Vt tile (h-major), 2 passes of 32 rows
        #pragma unroll
        for (int p = 0; p < 2; p++) {
            int rr = p * 32 + srow;
            *reinterpret_cast<bf16x8*>(&Klds[rr * LDP + scg * 8]) =
                *reinterpret_cast<const bf16x8*>(&kbuf[((size_t)b * 2048 + j * 64 + rr) * 64 + scg * 8]);
            *reinterpret_cast<bf16x8*>(&Vlds[rr * LDP + scg * 8]) =
                *reinterpret_cast<const bf16x8*>(&vtbuf[(size_t)b * 64 * 2048 + (size_t)rr * 2048 + j * 64 + scg * 8]);
        }
        __syncthreads();

        // S = Q K^T  (16 q x 64 kv per wave)
        f32x4 s[4];
        #pragma unroll
        for (int jf = 0; jf < 4; jf++) {
            f32x4 t = (f32x4){0.f, 0.f, 0.f, 0.f};
            #pragma unroll
            for (int kk = 0; kk < 2; kk++) {
                bf16x8 bk = *reinterpret_cast<const bf16x8*>(&Klds[(jf * 16 + cl) * LDP + kk * 32 + e0]);
                t = __builtin_amdgcn_mfma_f32_16x16x32_bf16(aq[kk], bk, t, 0, 0, 0);
            }
            s[jf] = t;
        }

        // scale + causal & padding (column) mask; per-row tile max
        float tmax[4] = {-INFINITY, -INFINITY, -INFINITY, -INFINITY};
        #pragma unroll
        for (int jf = 0; jf < 4; jf++) {
            int kv = j * 64 + jf * 16 + cl;
            int mk = mask[b * 2048 + kv];
            #pragma unroll
            for (int r = 0; r < 4; r++) {
                float sv = s[jf][r] * 0.125f;
                bool ok = (mk != 0) && (kv <= qbase + r0 + r);
                sv = ok ? sv : -INFINITY;
                s[jf][r] = sv;
                tmax[r] = fmaxf(tmax[r], sv);
            }
        }

        // online softmax: reduce across the 16 lanes holding this row's columns
        #pragma unroll
        for (int r = 0; r < 4; r++) {
            #pragma unroll
            for (int off = 1; off < 16; off <<= 1)
                tmax[r] = fmaxf(tmax[r], __shfl_xor(tmax[r], off));
            float mn = fmaxf(ms[r], tmax[r]);
            float alpha = (mn == -INFINITY) ? 1.0f : __expf(ms[r] - mn);
            float rs = 0.f;
            #pragma unroll
            for (int jf = 0; jf < 4; jf++) {
                float p = (mn == -INFINITY) ? 0.f : __expf(s[jf][r] - mn);
                s[jf][r] = p;
                rs += p;
            }
            #pragma unroll
            for (int off = 1; off < 16; off <<= 1)
                rs += __shfl_xor(rs, off);
            ls[r] = ls[r] * alpha + rs;
            ms[r] = mn;
            #pragma unroll
            for (int hf = 0; hf < 4; hf++) acc[hf][r] *= alpha;
        }

        // P -> wave-private LDS (to reach A-fragment layout), then O += P V
        #pragma unroll
        for (int jf = 0; jf < 4; jf++)
            #pragma unroll
            for (int r = 0; r < 4; r++)
                Plds[w][(r0 + r) * LDP + jf * 16 + cl] = (__bf16)s[jf][r];
        // same-wave LDS write->read: in-order DS pipe + compiler lgkmcnt; no barrier needed
        #pragma unroll
        for (int kk = 0; kk < 2; kk++) {
            bf16x8 ap = *reinterpret_cast<const bf16x8*>(&Plds[w][cl * LDP + kk * 32 + e0]);
            #pragma unroll
            for (int hf = 0; hf < 4; hf++) {
                bf16x8 bv = *reinterpret_cast<const bf16x8*>(&Vlds[(hf * 16 + cl) * LDP + kk * 32 + e0]);
                acc[hf] = __builtin_amdgcn_mfma_f32_16x16x32_bf16(ap, bv, acc[hf], 0, 0, 0);
            }
        }
        __syncthreads();  // before next tile overwrites K/V
    }

    // epilogue: normalize; apply ROW mask (mask[q]==0 -> fully-masked row -> 0,
    // matching reference nan_to_num); rows with l==0 (no valid keys) -> 0 too.
    #pragma unroll
    for (int hf = 0; hf < 4; hf++)
        #pragma unroll
        for (int r = 0; r < 4; r++) {
            int qrow = qbase + r0 + r;
            int mq = mask[b * 2048 + qrow];
            float l = ls[r];
            float v = (l > 0.f && mq != 0) ? acc[hf][r] / l : 0.f;
            out[((size_t)b * 2048 + qrow) * 64 + hf * 16 + cl] = v;
        }
}

extern "C" void kernel_launch(void* const* d_in, const int* in_sizes, int n_in,
                              void* d_out, int out_size, void* d_ws, size_t ws_size,
                              hipStream_t stream) {
    const float* x  = (const float*)d_in[0];
    const float* Wk = (const float*)d_in[1];
    const float* Wq = (const float*)d_in[2];
    const float* Wv = (const float*)d_in[3];
    const int* mask = (const int*)d_in[4];
    float* out = (float*)d_out;

    const size_t NTOK = 8 * 2048;          // 16384 rows
    __bf16* kbuf  = (__bf16*)d_ws;                    // [16384][64]
    __bf16* qbuf  = kbuf + NTOK * 64;                 // [16384][64]
    __bf16* vtbuf = qbuf + NTOK * 64;                 // [8][64][2048]

    proj_kernel<<<256, 512, 0, stream>>>(x, Wk, Wq, Wv, kbuf, qbuf, vtbuf);
    attn_kernel<<<dim3(32, 8), 256, 0, stream>>>(qbuf, kbuf, vtbuf, mask, out);
}

// Round 3
// 83.326 us; speedup vs baseline: 1.2806x; 1.2806x over previous
//
#include <hip/hip_runtime.h>
#include <hip/hip_bf16.h>

typedef __bf16 bf16x8 __attribute__((ext_vector_type(8)));
typedef float  f32x4  __attribute__((ext_vector_type(4)));

#define LDP 72  // padded LDS row stride in bf16 elems (144B): breaks 128B-stride bank conflicts, keeps 16B align

// ---------------- Kernel 1: fused QKV projection GEMM ----------------
// y[m, c] = sum_e x[m,e] * Wc[c,e];  c in [0,192): 0-63 -> k (Wk), 64-127 -> q (Wq), 128-191 -> v (Wv)
// Outputs: kbuf[m][64], qbuf[m][64] bf16 row-major; vtbuf[b][h][t] bf16 (V transposed per batch).
__global__ __launch_bounds__(512) void proj_kernel(
    const float* __restrict__ x, const float* __restrict__ Wk,
    const float* __restrict__ Wq, const float* __restrict__ Wv,
    __bf16* __restrict__ kbuf, __bf16* __restrict__ qbuf, __bf16* __restrict__ vtbuf)
{
    __shared__ __align__(16) __bf16 Alds[64 * LDP];    // x tile 64 rows x 64 k
    __shared__ __align__(16) __bf16 Wlds[192 * LDP];   // W tile 192 rows x 64 k
    __shared__ __align__(16) __bf16 Vtl[64 * LDP];     // v transpose buffer (h x t_rel)

    const int tid  = threadIdx.x;
    const int lane = tid & 63;
    const int wid  = tid >> 6;     // 0..7
    const int wm   = wid >> 2;     // 0..1 : M half (32 rows)
    const int wn   = wid & 3;      // 0..3 : N quarter (48 cols)
    const int mbase = blockIdx.x * 64;

    const int cl = lane & 15;          // fragment row/col lane index
    const int e0 = (lane >> 4) * 8;    // k-offset within 32-chunk
    const int r0 = (lane >> 4) * 4;    // C/D row group

    const int srow = tid >> 3;         // staging row 0..63
    const int scg  = tid & 7;          // staging 16B chunk 0..7

    f32x4 acc[2][3];
    #pragma unroll
    for (int i = 0; i < 2; i++)
        #pragma unroll
        for (int j = 0; j < 3; j++) acc[i][j] = (f32x4){0.f, 0.f, 0.f, 0.f};

    for (int kb = 0; kb < 1024; kb += 64) {
        // stage A: 64x64 fp32 -> bf16
        {
            const float* src = x + (size_t)(mbase + srow) * 1024 + kb + scg * 8;
            float4 f0 = *reinterpret_cast<const float4*>(src);
            float4 f1 = *reinterpret_cast<const float4*>(src + 4);
            bf16x8 v;
            v[0] = (__bf16)f0.x; v[1] = (__bf16)f0.y; v[2] = (__bf16)f0.z; v[3] = (__bf16)f0.w;
            v[4] = (__bf16)f1.x; v[5] = (__bf16)f1.y; v[6] = (__bf16)f1.z; v[7] = (__bf16)f1.w;
            *reinterpret_cast<bf16x8*>(&Alds[srow * LDP + scg * 8]) = v;
        }
        // stage W: 3 passes (Wk, Wq, Wv), 64 rows each
        #pragma unroll
        for (int p = 0; p < 3; p++) {
            const float* wp = (p == 0) ? Wk : (p == 1) ? Wq : Wv;
            const float* src = wp + (size_t)srow * 1024 + kb + scg * 8;
            float4 f0 = *reinterpret_cast<const float4*>(src);
            float4 f1 = *reinterpret_cast<const float4*>(src + 4);
            bf16x8 v;
            v[0] = (__bf16)f0.x; v[1] = (__bf16)f0.y; v[2] = (__bf16)f0.z; v[3] = (__bf16)f0.w;
            v[4] = (__bf16)f1.x; v[5] = (__bf16)f1.y; v[6] = (__bf16)f1.z; v[7] = (__bf16)f1.w;
            *reinterpret_cast<bf16x8*>(&Wlds[(p * 64 + srow) * LDP + scg * 8]) = v;
        }
        __syncthreads();
        #pragma unroll
        for (int kk = 0; kk < 2; kk++) {
            bf16x8 a[2], bb[3];
            #pragma unroll
            for (int mf = 0; mf < 2; mf++)
                a[mf] = *reinterpret_cast<const bf16x8*>(&Alds[(wm * 32 + mf * 16 + cl) * LDP + kk * 32 + e0]);
            #pragma unroll
            for (int nf = 0; nf < 3; nf++)
                bb[nf] = *reinterpret_cast<const bf16x8*>(&Wlds[(wn * 48 + nf * 16 + cl) * LDP + kk * 32 + e0]);
            #pragma unroll
            for (int mf = 0; mf < 2; mf++)
                #pragma unroll
                for (int nf = 0; nf < 3; nf++)
                    acc[mf][nf] = __builtin_amdgcn_mfma_f32_16x16x32_bf16(a[mf], bb[nf], acc[mf][nf], 0, 0, 0);
        }
        __syncthreads();
    }

    // epilogue: k,q direct bf16 stores; v -> LDS transpose -> vtbuf
    #pragma unroll
    for (int mf = 0; mf < 2; mf++)
        #pragma unroll
        for (int nf = 0; nf < 3; nf++) {
            int c = wn * 48 + nf * 16 + cl;
            #pragma unroll
            for (int r = 0; r < 4; r++) {
                int mrel = wm * 32 + mf * 16 + r0 + r;
                float v = acc[mf][nf][r];
                if (c < 64)        kbuf[(size_t)(mbase + mrel) * 64 + c]         = (__bf16)v;
                else if (c < 128)  qbuf[(size_t)(mbase + mrel) * 64 + (c - 64)]  = (__bf16)v;
                else               Vtl[(c - 128) * LDP + mrel]                   = (__bf16)v;
            }
        }
    __syncthreads();
    {
        int b   = mbase >> 11;       // 2048 rows per batch
        int tof = mbase & 2047;
        bf16x8 v8 = *reinterpret_cast<const bf16x8*>(&Vtl[srow * LDP + scg * 8]);
        *reinterpret_cast<bf16x8*>(&vtbuf[(size_t)b * 64 * 2048 + (size_t)srow * 2048 + tof + scg * 8]) = v8;
    }
}

// ---------------- Kernel 2: flash attention, split over the KV axis ----------------
// grid (32 q-tiles, nsplit, 8 batches), 256 threads = 4 waves; wave w owns 16 q rows.
// Split sp handles KV tiles [sp*tps, min((sp+1)*tps, qt+1)). nsplit==1 writes out
// directly; nsplit>1 writes unnormalized partials (acc, m, l) for the combine kernel.
// Padding mask is an OUTER PRODUCT mask[q]*mask[k]: column mask applied in-loop,
// row mask at the final write (fully-masked rows -> 0, matching nan_to_num).
__global__ __launch_bounds__(256) void attn_kernel(
    const __bf16* __restrict__ qbuf, const __bf16* __restrict__ kbuf,
    const __bf16* __restrict__ vtbuf, const int* __restrict__ mask,
    float* __restrict__ out, float* __restrict__ accpart, float* __restrict__ mlpart,
    int nsplit, int tps)
{
    __shared__ __align__(16) __bf16 Klds[64 * LDP];     // kv rows x 64 h
    __shared__ __align__(16) __bf16 Vlds[64 * LDP];     // h rows x 64 kv  (from vtbuf)
    __shared__ __align__(16) __bf16 Plds[4][16 * LDP];  // per-wave P tile: 16 q x 64 kv

    const int tid  = threadIdx.x;
    const int lane = tid & 63;
    const int w    = tid >> 6;
    const int qt   = blockIdx.x;
    const int sp   = blockIdx.y;
    const int b    = blockIdx.z;
    const int qbase = qt * 64 + w * 16;

    const int jbeg = sp * tps;
    const int jend = min((sp + 1) * tps, qt + 1);

    if (nsplit > 1 && jbeg >= jend) {
        // empty split: write zero partials (ws is poisoned; combine reads everything)
        float* ap = accpart + ((size_t)(b * nsplit + sp) * 2048 + qt * 64) * 64;
        for (int i = tid; i < 64 * 64; i += 256) ap[i] = 0.f;
        float* mp = mlpart + ((size_t)(b * nsplit + sp) * 2048 + qt * 64) * 2;
        for (int i = tid; i < 64; i += 256) { mp[2 * i] = -INFINITY; mp[2 * i + 1] = 0.f; }
        return;
    }

    const int cl = lane & 15;
    const int e0 = (lane >> 4) * 8;
    const int r0 = (lane >> 4) * 4;

    // Q fragments held in registers for the whole kernel
    bf16x8 aq[2];
    #pragma unroll
    for (int kk = 0; kk < 2; kk++)
        aq[kk] = *reinterpret_cast<const bf16x8*>(&qbuf[((size_t)b * 2048 + qbase + cl) * 64 + kk * 32 + e0]);

    float ms[4], ls[4];
    f32x4 acc[4];
    #pragma unroll
    for (int r = 0; r < 4; r++) { ms[r] = -INFINITY; ls[r] = 0.f; }
    #pragma unroll
    for (int hf = 0; hf < 4; hf++) acc[hf] = (f32x4){0.f, 0.f, 0.f, 0.f};

    const int srow = tid >> 3;   // 0..31
    const int scg  = tid & 7;

    for (int j = jbeg; j < jend; j++) {
        // stage K tile (kv-major) and Vt tile (h-major), 2 passes of 32 rows
        #pragma unroll
        for (int p = 0; p < 2; p++) {
            int rr = p * 32 + srow;
            *reinterpret_cast<bf16x8*>(&Klds[rr * LDP + scg * 8]) =
                *reinterpret_cast<const bf16x8*>(&kbuf[((size_t)b * 2048 + j * 64 + rr) * 64 + scg * 8]);
            *reinterpret_cast<bf16x8*>(&Vlds[rr * LDP + scg * 8]) =
                *reinterpret_cast<const bf16x8*>(&vtbuf[(size_t)b * 64 * 2048 + (size_t)rr * 2048 + j * 64 + scg * 8]);
        }
        __syncthreads();

        // S = Q K^T  (16 q x 64 kv per wave)
        f32x4 s[4];
        #pragma unroll
        for (int jf = 0; jf < 4; jf++) {
            f32x4 t = (f32x4){0.f, 0.f, 0.f, 0.f};
            #pragma unroll
            for (int kk = 0; kk < 2; kk++) {
                bf16x8 bk = *reinterpret_cast<const bf16x8*>(&Klds[(jf * 16 + cl) * LDP + kk * 32 + e0]);
                t = __builtin_amdgcn_mfma_f32_16x16x32_bf16(aq[kk], bk, t, 0, 0, 0);
            }
            s[jf] = t;
        }

        // scale + causal & padding (column) mask; per-row tile max
        float tmax[4] = {-INFINITY, -INFINITY, -INFINITY, -INFINITY};
        #pragma unroll
        for (int jf = 0; jf < 4; jf++) {
            int kv = j * 64 + jf * 16 + cl;
            int mk = mask[b * 2048 + kv];
            #pragma unroll
            for (int r = 0; r < 4; r++) {
                float sv = s[jf][r] * 0.125f;
                bool ok = (mk != 0) && (kv <= qbase + r0 + r);
                sv = ok ? sv : -INFINITY;
                s[jf][r] = sv;
                tmax[r] = fmaxf(tmax[r], sv);
            }
        }

        // online softmax: reduce across the 16 lanes holding this row's columns
        #pragma unroll
        for (int r = 0; r < 4; r++) {
            #pragma unroll
            for (int off = 1; off < 16; off <<= 1)
                tmax[r] = fmaxf(tmax[r], __shfl_xor(tmax[r], off));
            float mn = fmaxf(ms[r], tmax[r]);
            float alpha = (mn == -INFINITY) ? 1.0f : __expf(ms[r] - mn);
            float rs = 0.f;
            #pragma unroll
            for (int jf = 0; jf < 4; jf++) {
                float p = (mn == -INFINITY) ? 0.f : __expf(s[jf][r] - mn);
                s[jf][r] = p;
                rs += p;
            }
            #pragma unroll
            for (int off = 1; off < 16; off <<= 1)
                rs += __shfl_xor(rs, off);
            ls[r] = ls[r] * alpha + rs;
            ms[r] = mn;
            #pragma unroll
            for (int hf = 0; hf < 4; hf++) acc[hf][r] *= alpha;
        }

        // P -> wave-private LDS (to reach A-fragment layout), then O += P V
        #pragma unroll
        for (int jf = 0; jf < 4; jf++)
            #pragma unroll
            for (int r = 0; r < 4; r++)
                Plds[w][(r0 + r) * LDP + jf * 16 + cl] = (__bf16)s[jf][r];
        // same-wave LDS write->read: in-order DS pipe + compiler lgkmcnt; no barrier needed
        #pragma unroll
        for (int kk = 0; kk < 2; kk++) {
            bf16x8 ap = *reinterpret_cast<const bf16x8*>(&Plds[w][cl * LDP + kk * 32 + e0]);
            #pragma unroll
            for (int hf = 0; hf < 4; hf++) {
                bf16x8 bv = *reinterpret_cast<const bf16x8*>(&Vlds[(hf * 16 + cl) * LDP + kk * 32 + e0]);
                acc[hf] = __builtin_amdgcn_mfma_f32_16x16x32_bf16(ap, bv, acc[hf], 0, 0, 0);
            }
        }
        __syncthreads();  // before next tile overwrites K/V
    }

    if (nsplit == 1) {
        // direct epilogue: normalize; row mask (mask[q]==0 -> 0, matching nan_to_num)
        #pragma unroll
        for (int hf = 0; hf < 4; hf++)
            #pragma unroll
            for (int r = 0; r < 4; r++) {
                int qrow = qbase + r0 + r;
                int mq = mask[b * 2048 + qrow];
                float l = ls[r];
                float v = (l > 0.f && mq != 0) ? acc[hf][r] / l : 0.f;
                out[((size_t)b * 2048 + qrow) * 64 + hf * 16 + cl] = v;
            }
    } else {
        // partial epilogue: unnormalized acc + (m, l) per row
        #pragma unroll
        for (int hf = 0; hf < 4; hf++)
            #pragma unroll
            for (int r = 0; r < 4; r++) {
                int qrow = qbase + r0 + r;
                accpart[((size_t)(b * nsplit + sp) * 2048 + qrow) * 64 + hf * 16 + cl] = acc[hf][r];
            }
        if (cl == 0) {
            #pragma unroll
            for (int r = 0; r < 4; r++) {
                int qrow = qbase + r0 + r;
                mlpart[((size_t)(b * nsplit + sp) * 2048 + qrow) * 2 + 0] = ms[r];
                mlpart[((size_t)(b * nsplit + sp) * 2048 + qrow) * 2 + 1] = ls[r];
            }
        }
    }
}

// ---------------- Kernel 3: combine split partials ----------------
// thread per (q row, h): out = sum_s exp(m_s - M) acc_s / sum_s exp(m_s - M) l_s
__global__ __launch_bounds__(256) void combine_kernel(
    const float* __restrict__ accpart, const float* __restrict__ mlpart,
    const int* __restrict__ mask, float* __restrict__ out, int nsplit)
{
    int idx = blockIdx.x * 256 + threadIdx.x;   // 0 .. 16384*64-1
    int qglob = idx >> 6;                        // = b*2048 + qrow
    int h = idx & 63;
    int b = qglob >> 11;
    int qrow = qglob & 2047;

    if (mask[qglob] == 0) { out[idx] = 0.f; return; }

    float m_s[4], l_s[4];
    float M = -INFINITY;
    for (int s = 0; s < nsplit; s++) {
        size_t mo = ((size_t)(b * nsplit + s) * 2048 + qrow) * 2;
        m_s[s] = mlpart[mo];
        l_s[s] = mlpart[mo + 1];
        M = fmaxf(M, m_s[s]);
    }
    if (M == -INFINITY) { out[idx] = 0.f; return; }

    float L = 0.f, O = 0.f;
    for (int s = 0; s < nsplit; s++) {
        float wgt = (m_s[s] == -INFINITY) ? 0.f : __expf(m_s[s] - M);
        L += l_s[s] * wgt;
        O += wgt * accpart[((size_t)(b * nsplit + s) * 2048 + qrow) * 64 + h];
    }
    out[idx] = (L > 0.f) ? O / L : 0.f;
}

extern "C" void kernel_launch(void* const* d_in, const int* in_sizes, int n_in,
                              void* d_out, int out_size, void* d_ws, size_t ws_size,
                              hipStream_t stream) {
    const float* x  = (const float*)d_in[0];
    const float* Wk = (const float*)d_in[1];
    const float* Wq = (const float*)d_in[2];
    const float* Wv = (const float*)d_in[3];
    const int* mask = (const int*)d_in[4];
    float* out = (float*)d_out;

    const size_t NTOK = 8 * 2048;          // 16384 rows
    __bf16* kbuf  = (__bf16*)d_ws;                    // [16384][64]
    __bf16* qbuf  = kbuf + NTOK * 64;                 // [16384][64]
    __bf16* vtbuf = qbuf + NTOK * 64;                 // [8][64][2048]
    const size_t base_bytes = NTOK * 64 * 2 * 2 + (size_t)8 * 64 * 2048 * 2;  // 6,291,456

    // pick split count from available workspace (deterministic: ws_size is fixed)
    const size_t acc_per_split = NTOK * 64 * 4;       // 4 MiB
    const size_t ml_per_split  = NTOK * 2 * 4;        // 128 KiB
    int nsplit = 1;
    if (ws_size >= base_bytes + 4 * (acc_per_split + ml_per_split))      nsplit = 4;
    else if (ws_size >= base_bytes + 2 * (acc_per_split + ml_per_split)) nsplit = 2;

    float* accpart = (float*)((char*)d_ws + base_bytes);
    float* mlpart  = accpart + NTOK * 64 * nsplit;

    proj_kernel<<<256, 512, 0, stream>>>(x, Wk, Wq, Wv, kbuf, qbuf, vtbuf);
    attn_kernel<<<dim3(32, nsplit, 8), 256, 0, stream>>>(
        qbuf, kbuf, vtbuf, mask, out, accpart, mlpart, nsplit, 32 / nsplit);
    if (nsplit > 1)
        combine_kernel<<<(16384 * 64) / 256, 256, 0, stream>>>(accpart, mlpart, mask, out, nsplit);
}

// Round 4
// 73.465 us; speedup vs baseline: 1.4525x; 1.1342x over previous
//
#include <hip/hip_runtime.h>
#include <hip/hip_bf16.h>

typedef __bf16 bf16x8 __attribute__((ext_vector_type(8)));
typedef __bf16 bf16x4 __attribute__((ext_vector_type(4)));
typedef float  f32x4  __attribute__((ext_vector_type(4)));

#define LDP 72  // padded LDS row stride in bf16 elems (144B): breaks 128B-stride bank conflicts, keeps 16B align

// ---------------- Kernel 1: fused QKV projection GEMM (pipelined) ----------------
// y[m, c] = sum_e x[m,e] * Wc[c,e];  c in [0,192): 0-63 -> k, 64-127 -> q, 128-191 -> v
// 1024 threads = 16 waves (4/SIMD for latency overlap); wave = 16 rows x 48 cols.
// Reg-staged double-buffered LDS pipeline: global loads for K-block j+1 are in
// flight during MFMA of block j; one barrier per iteration.
__global__ __launch_bounds__(1024) void proj_kernel(
    const float* __restrict__ x, const float* __restrict__ Wk,
    const float* __restrict__ Wq, const float* __restrict__ Wv,
    __bf16* __restrict__ kbuf, __bf16* __restrict__ qbuf, __bf16* __restrict__ vtbuf)
{
    // rows 0..63: A (x tile); rows 64..255: W (Wk|Wq|Wv), 64 k-cols each, double-buffered
    __shared__ __align__(16) __bf16 Slds[2][256 * LDP];   // 2 x 36 KB
    __shared__ __align__(16) __bf16 Vtl[64 * LDP];        // v transpose staging (epilogue only)

    const int tid  = threadIdx.x;
    const int lane = tid & 63;
    const int wid  = tid >> 6;     // 0..15
    const int wm   = wid >> 2;     // 0..3 : 16-row group
    const int wn   = wid & 3;      // 0..3 : 48-col group
    const int mbase = blockIdx.x * 64;

    const int cl = lane & 15;          // fragment row/col lane index
    const int e0 = (lane >> 4) * 8;    // k-offset within 32-chunk
    const int r0 = (lane >> 4) * 4;    // C/D row group

    // staging: thread t owns row srow (0..255), 16 consecutive fp32 at col scg*16
    const int srow = tid >> 2;
    const int scg  = tid & 3;
    const float* sptr;
    if (srow < 64) {
        sptr = x + (size_t)(mbase + srow) * 1024 + scg * 16;
    } else {
        int wr = srow - 64;                       // 0..191
        const float* wp = (wr < 64) ? Wk : (wr < 128) ? Wq : Wv;
        sptr = wp + (size_t)(wr & 63) * 1024 + scg * 16;
    }
    __bf16* myld0 = &Slds[0][srow * LDP + scg * 16];
    __bf16* myld1 = &Slds[1][srow * LDP + scg * 16];

    float4 pf0, pf1, pf2, pf3;  // in-flight K-block (64B/thread)

#define ISSUE(kb) { const float* p_ = sptr + (kb); \
    pf0 = *reinterpret_cast<const float4*>(p_); \
    pf1 = *reinterpret_cast<const float4*>(p_ + 4); \
    pf2 = *reinterpret_cast<const float4*>(p_ + 8); \
    pf3 = *reinterpret_cast<const float4*>(p_ + 12); }

#define COMMIT(dst) { bf16x8 v0_, v1_; \
    v0_[0]=(__bf16)pf0.x; v0_[1]=(__bf16)pf0.y; v0_[2]=(__bf16)pf0.z; v0_[3]=(__bf16)pf0.w; \
    v0_[4]=(__bf16)pf1.x; v0_[5]=(__bf16)pf1.y; v0_[6]=(__bf16)pf1.z; v0_[7]=(__bf16)pf1.w; \
    v1_[0]=(__bf16)pf2.x; v1_[1]=(__bf16)pf2.y; v1_[2]=(__bf16)pf2.z; v1_[3]=(__bf16)pf2.w; \
    v1_[4]=(__bf16)pf3.x; v1_[5]=(__bf16)pf3.y; v1_[6]=(__bf16)pf3.z; v1_[7]=(__bf16)pf3.w; \
    *reinterpret_cast<bf16x8*>(dst) = v0_; \
    *reinterpret_cast<bf16x8*>((dst) + 8) = v1_; }

    f32x4 acc[3];
    #pragma unroll
    for (int n = 0; n < 3; n++) acc[n] = (f32x4){0.f, 0.f, 0.f, 0.f};

    // prologue: fill buf0 with kb=0, start kb=1
    ISSUE(0);
    COMMIT(myld0);
    ISSUE(64);
    __syncthreads();

    for (int j = 0; j < 16; j++) {
        const __bf16* buf = Slds[j & 1];
        // compute on current buffer; next K-block's loads are in flight
        #pragma unroll
        for (int kk = 0; kk < 2; kk++) {
            bf16x8 a = *reinterpret_cast<const bf16x8*>(&buf[(wm * 16 + cl) * LDP + kk * 32 + e0]);
            #pragma unroll
            for (int nf = 0; nf < 3; nf++) {
                bf16x8 b = *reinterpret_cast<const bf16x8*>(&buf[(64 + wn * 48 + nf * 16 + cl) * LDP + kk * 32 + e0]);
                acc[nf] = __builtin_amdgcn_mfma_f32_16x16x32_bf16(a, b, acc[nf], 0, 0, 0);
            }
        }
        if (j < 15) {
            COMMIT((j & 1) ? myld0 : myld1);   // write OTHER buffer: no read hazard
            if (j < 14) ISSUE((j + 2) * 64);
        }
        __syncthreads();
    }

    // epilogue: k,q direct bf16 stores; v -> LDS transpose -> vtbuf
    #pragma unroll
    for (int nf = 0; nf < 3; nf++) {
        int c = wn * 48 + nf * 16 + cl;
        #pragma unroll
        for (int r = 0; r < 4; r++) {
            int mrel = wm * 16 + r0 + r;
            float v = acc[nf][r];
            if (c < 64)        kbuf[(size_t)(mbase + mrel) * 64 + c]         = (__bf16)v;
            else if (c < 128)  qbuf[(size_t)(mbase + mrel) * 64 + (c - 64)]  = (__bf16)v;
            else               Vtl[(c - 128) * LDP + mrel]                   = (__bf16)v;
        }
    }
    __syncthreads();
    {
        int b   = mbase >> 11;       // 2048 rows per batch
        int tof = mbase & 2047;
        int h   = tid >> 4;          // 0..63
        int seg = tid & 15;          // 4 bf16 each
        bf16x4 v4 = *reinterpret_cast<const bf16x4*>(&Vtl[h * LDP + seg * 4]);
        *reinterpret_cast<bf16x4*>(&vtbuf[(size_t)b * 64 * 2048 + (size_t)h * 2048 + tof + seg * 4]) = v4;
    }
#undef ISSUE
#undef COMMIT
}

// ---------------- Kernel 2: flash attention, split over the KV axis ----------------
// grid (32 q-tiles, nsplit, 8 batches), 256 threads = 4 waves; wave w owns 16 q rows.
// Split sp handles KV tiles [sp*tps, min((sp+1)*tps, qt+1)). nsplit==1 writes out
// directly; nsplit>1 writes unnormalized partials (acc, m, l) for the combine kernel.
// Padding mask is an OUTER PRODUCT mask[q]*mask[k]: column mask applied in-loop,
// row mask at the final write (fully-masked rows -> 0, matching nan_to_num).
__global__ __launch_bounds__(256) void attn_kernel(
    const __bf16* __restrict__ qbuf, const __bf16* __restrict__ kbuf,
    const __bf16* __restrict__ vtbuf, const int* __restrict__ mask,
    float* __restrict__ out, float* __restrict__ accpart, float* __restrict__ mlpart,
    int nsplit, int tps)
{
    __shared__ __align__(16) __bf16 Klds[64 * LDP];     // kv rows x 64 h
    __shared__ __align__(16) __bf16 Vlds[64 * LDP];     // h rows x 64 kv  (from vtbuf)
    __shared__ __align__(16) __bf16 Plds[4][16 * LDP];  // per-wave P tile: 16 q x 64 kv

    const int tid  = threadIdx.x;
    const int lane = tid & 63;
    const int w    = tid >> 6;
    const int qt   = blockIdx.x;
    const int sp   = blockIdx.y;
    const int b    = blockIdx.z;
    const int qbase = qt * 64 + w * 16;

    const int jbeg = sp * tps;
    const int jend = min((sp + 1) * tps, qt + 1);

    if (nsplit > 1 && jbeg >= jend) {
        // empty split: write zero partials (ws is poisoned; combine reads everything)
        float* ap = accpart + ((size_t)(b * nsplit + sp) * 2048 + qt * 64) * 64;
        for (int i = tid; i < 64 * 64; i += 256) ap[i] = 0.f;
        float* mp = mlpart + ((size_t)(b * nsplit + sp) * 2048 + qt * 64) * 2;
        for (int i = tid; i < 64; i += 256) { mp[2 * i] = -INFINITY; mp[2 * i + 1] = 0.f; }
        return;
    }

    const int cl = lane & 15;
    const int e0 = (lane >> 4) * 8;
    const int r0 = (lane >> 4) * 4;

    // Q fragments held in registers for the whole kernel
    bf16x8 aq[2];
    #pragma unroll
    for (int kk = 0; kk < 2; kk++)
        aq[kk] = *reinterpret_cast<const bf16x8*>(&qbuf[((size_t)b * 2048 + qbase + cl) * 64 + kk * 32 + e0]);

    float ms[4], ls[4];
    f32x4 acc[4];
    #pragma unroll
    for (int r = 0; r < 4; r++) { ms[r] = -INFINITY; ls[r] = 0.f; }
    #pragma unroll
    for (int hf = 0; hf < 4; hf++) acc[hf] = (f32x4){0.f, 0.f, 0.f, 0.f};

    const int srow = tid >> 3;   // 0..31
    const int scg  = tid & 7;

    for (int j = jbeg; j < jend; j++) {
        // stage K tile (kv-major) and Vt tile (h-major), 2 passes of 32 rows
        #pragma unroll
        for (int p = 0; p < 2; p++) {
            int rr = p * 32 + srow;
            *reinterpret_cast<bf16x8*>(&Klds[rr * LDP + scg * 8]) =
                *reinterpret_cast<const bf16x8*>(&kbuf[((size_t)b * 2048 + j * 64 + rr) * 64 + scg * 8]);
            *reinterpret_cast<bf16x8*>(&Vlds[rr * LDP + scg * 8]) =
                *reinterpret_cast<const bf16x8*>(&vtbuf[(size_t)b * 64 * 2048 + (size_t)rr * 2048 + j * 64 + scg * 8]);
        }
        __syncthreads();

        // S = Q K^T  (16 q x 64 kv per wave)
        f32x4 s[4];
        #pragma unroll
        for (int jf = 0; jf < 4; jf++) {
            f32x4 t = (f32x4){0.f, 0.f, 0.f, 0.f};
            #pragma unroll
            for (int kk = 0; kk < 2; kk++) {
                bf16x8 bk = *reinterpret_cast<const bf16x8*>(&Klds[(jf * 16 + cl) * LDP + kk * 32 + e0]);
                t = __builtin_amdgcn_mfma_f32_16x16x32_bf16(aq[kk], bk, t, 0, 0, 0);
            }
            s[jf] = t;
        }

        // scale + causal & padding (column) mask; per-row tile max
        float tmax[4] = {-INFINITY, -INFINITY, -INFINITY, -INFINITY};
        #pragma unroll
        for (int jf = 0; jf < 4; jf++) {
            int kv = j * 64 + jf * 16 + cl;
            int mk = mask[b * 2048 + kv];
            #pragma unroll
            for (int r = 0; r < 4; r++) {
                float sv = s[jf][r] * 0.125f;
                bool ok = (mk != 0) && (kv <= qbase + r0 + r);
                sv = ok ? sv : -INFINITY;
                s[jf][r] = sv;
                tmax[r] = fmaxf(tmax[r], sv);
            }
        }

        // online softmax: reduce across the 16 lanes holding this row's columns
        #pragma unroll
        for (int r = 0; r < 4; r++) {
            #pragma unroll
            for (int off = 1; off < 16; off <<= 1)
                tmax[r] = fmaxf(tmax[r], __shfl_xor(tmax[r], off));
            float mn = fmaxf(ms[r], tmax[r]);
            float alpha = (mn == -INFINITY) ? 1.0f : __expf(ms[r] - mn);
            float rs = 0.f;
            #pragma unroll
            for (int jf = 0; jf < 4; jf++) {
                float p = (mn == -INFINITY) ? 0.f : __expf(s[jf][r] - mn);
                s[jf][r] = p;
                rs += p;
            }
            #pragma unroll
            for (int off = 1; off < 16; off <<= 1)
                rs += __shfl_xor(rs, off);
            ls[r] = ls[r] * alpha + rs;
            ms[r] = mn;
            #pragma unroll
            for (int hf = 0; hf < 4; hf++) acc[hf][r] *= alpha;
        }

        // P -> wave-private LDS (to reach A-fragment layout), then O += P V
        #pragma unroll
        for (int jf = 0; jf < 4; jf++)
            #pragma unroll
            for (int r = 0; r < 4; r++)
                Plds[w][(r0 + r) * LDP + jf * 16 + cl] = (__bf16)s[jf][r];
        // same-wave LDS write->read: in-order DS pipe + compiler lgkmcnt; no barrier needed
        #pragma unroll
        for (int kk = 0; kk < 2; kk++) {
            bf16x8 ap = *reinterpret_cast<const bf16x8*>(&Plds[w][cl * LDP + kk * 32 + e0]);
            #pragma unroll
            for (int hf = 0; hf < 4; hf++) {
                bf16x8 bv = *reinterpret_cast<const bf16x8*>(&Vlds[(hf * 16 + cl) * LDP + kk * 32 + e0]);
                acc[hf] = __builtin_amdgcn_mfma_f32_16x16x32_bf16(ap, bv, acc[hf], 0, 0, 0);
            }
        }
        __syncthreads();  // before next tile overwrites K/V
    }

    if (nsplit == 1) {
        // direct epilogue: normalize; row mask (mask[q]==0 -> 0, matching nan_to_num)
        #pragma unroll
        for (int hf = 0; hf < 4; hf++)
            #pragma unroll
            for (int r = 0; r < 4; r++) {
                int qrow = qbase + r0 + r;
                int mq = mask[b * 2048 + qrow];
                float l = ls[r];
                float v = (l > 0.f && mq != 0) ? acc[hf][r] / l : 0.f;
                out[((size_t)b * 2048 + qrow) * 64 + hf * 16 + cl] = v;
            }
    } else {
        // partial epilogue: unnormalized acc + (m, l) per row
        #pragma unroll
        for (int hf = 0; hf < 4; hf++)
            #pragma unroll
            for (int r = 0; r < 4; r++) {
                int qrow = qbase + r0 + r;
                accpart[((size_t)(b * nsplit + sp) * 2048 + qrow) * 64 + hf * 16 + cl] = acc[hf][r];
            }
        if (cl == 0) {
            #pragma unroll
            for (int r = 0; r < 4; r++) {
                int qrow = qbase + r0 + r;
                mlpart[((size_t)(b * nsplit + sp) * 2048 + qrow) * 2 + 0] = ms[r];
                mlpart[((size_t)(b * nsplit + sp) * 2048 + qrow) * 2 + 1] = ls[r];
            }
        }
    }
}

// ---------------- Kernel 3: combine split partials ----------------
// thread per (q row, h): out = sum_s exp(m_s - M) acc_s / sum_s exp(m_s - M) l_s
__global__ __launch_bounds__(256) void combine_kernel(
    const float* __restrict__ accpart, const float* __restrict__ mlpart,
    const int* __restrict__ mask, float* __restrict__ out, int nsplit)
{
    int idx = blockIdx.x * 256 + threadIdx.x;   // 0 .. 16384*64-1
    int qglob = idx >> 6;                        // = b*2048 + qrow
    int h = idx & 63;
    int b = qglob >> 11;
    int qrow = qglob & 2047;

    if (mask[qglob] == 0) { out[idx] = 0.f; return; }

    float m_s[4], l_s[4];
    float M = -INFINITY;
    for (int s = 0; s < nsplit; s++) {
        size_t mo = ((size_t)(b * nsplit + s) * 2048 + qrow) * 2;
        m_s[s] = mlpart[mo];
        l_s[s] = mlpart[mo + 1];
        M = fmaxf(M, m_s[s]);
    }
    if (M == -INFINITY) { out[idx] = 0.f; return; }

    float L = 0.f, O = 0.f;
    for (int s = 0; s < nsplit; s++) {
        float wgt = (m_s[s] == -INFINITY) ? 0.f : __expf(m_s[s] - M);
        L += l_s[s] * wgt;
        O += wgt * accpart[((size_t)(b * nsplit + s) * 2048 + qrow) * 64 + h];
    }
    out[idx] = (L > 0.f) ? O / L : 0.f;
}

extern "C" void kernel_launch(void* const* d_in, const int* in_sizes, int n_in,
                              void* d_out, int out_size, void* d_ws, size_t ws_size,
                              hipStream_t stream) {
    const float* x  = (const float*)d_in[0];
    const float* Wk = (const float*)d_in[1];
    const float* Wq = (const float*)d_in[2];
    const float* Wv = (const float*)d_in[3];
    const int* mask = (const int*)d_in[4];
    float* out = (float*)d_out;

    const size_t NTOK = 8 * 2048;          // 16384 rows
    __bf16* kbuf  = (__bf16*)d_ws;                    // [16384][64]
    __bf16* qbuf  = kbuf + NTOK * 64;                 // [16384][64]
    __bf16* vtbuf = qbuf + NTOK * 64;                 // [8][64][2048]
    const size_t base_bytes = NTOK * 64 * 2 * 2 + (size_t)8 * 64 * 2048 * 2;  // 6,291,456

    // pick split count from available workspace (deterministic: ws_size is fixed)
    const size_t acc_per_split = NTOK * 64 * 4;       // 4 MiB
    const size_t ml_per_split  = NTOK * 2 * 4;        // 128 KiB
    int nsplit = 1;
    if (ws_size >= base_bytes + 4 * (acc_per_split + ml_per_split))      nsplit = 4;
    else if (ws_size >= base_bytes + 2 * (acc_per_split + ml_per_split)) nsplit = 2;

    float* accpart = (float*)((char*)d_ws + base_bytes);
    float* mlpart  = accpart + NTOK * 64 * nsplit;

    proj_kernel<<<256, 1024, 0, stream>>>(x, Wk, Wq, Wv, kbuf, qbuf, vtbuf);
    attn_kernel<<<dim3(32, nsplit, 8), 256, 0, stream>>>(
        qbuf, kbuf, vtbuf, mask, out, accpart, mlpart, nsplit, 32 / nsplit);
    if (nsplit > 1)
        combine_kernel<<<(16384 * 64) / 256, 256, 0, stream>>>(accpart, mlpart, mask, out, nsplit);
}

// Round 5
// 67.024 us; speedup vs baseline: 1.5921x; 1.0961x over previous
//
#include <hip/hip_runtime.h>
#include <hip/hip_bf16.h>

typedef __bf16 bf16x8 __attribute__((ext_vector_type(8)));
typedef __bf16 bf16x4 __attribute__((ext_vector_type(4)));
typedef float  f32x4  __attribute__((ext_vector_type(4)));

#define LDP 72  // padded LDS row stride in bf16 elems (144B): breaks 128B-stride bank conflicts, keeps 16B align

// ---------------- Kernel 0: W -> bf16 pre-conversion ----------------
// wbf[192][1024]: rows 0-63 Wk, 64-127 Wq, 128-191 Wv. Halves the per-block W
// re-read traffic in proj (W is re-fetched by every block: 256 x 768KB fp32 was
// 192MB of the 256MB total -> now 96MB bf16).
__global__ __launch_bounds__(256) void wconv_kernel(
    const float* __restrict__ Wk, const float* __restrict__ Wq,
    const float* __restrict__ Wv, __bf16* __restrict__ wbf)
{
    int idx = blockIdx.x * 256 + threadIdx.x;      // 0 .. 49151 (192*1024/4)
    int row = idx >> 8;                             // 256 float4-chunks per row
    int c4  = idx & 255;
    const float* wp = (row < 64) ? Wk + (size_t)row * 1024
                    : (row < 128) ? Wq + (size_t)(row - 64) * 1024
                                  : Wv + (size_t)(row - 128) * 1024;
    float4 f = *reinterpret_cast<const float4*>(wp + c4 * 4);
    bf16x4 v; v[0] = (__bf16)f.x; v[1] = (__bf16)f.y; v[2] = (__bf16)f.z; v[3] = (__bf16)f.w;
    *reinterpret_cast<bf16x4*>(&wbf[(size_t)row * 1024 + c4 * 4]) = v;
}

// ---------------- Kernel 1: fused QKV projection GEMM (depth-2 pipeline) ----------------
// y[m, c] = sum_e x[m,e] * wbf[c,e]; c in [0,192): k | q | v. 1024 threads = 16 waves,
// wave = 16 rows x 48 cols. Two register prefetch sets (parity-unrolled -> static
// indexing), double-buffered LDS, one barrier/iter. Loads have ~2 iterations in flight.
__global__ __launch_bounds__(1024) void proj_kernel(
    const float* __restrict__ x, const __bf16* __restrict__ wbf,
    __bf16* __restrict__ kbuf, __bf16* __restrict__ qbuf, __bf16* __restrict__ vtbuf)
{
    // rows 0..63: A (x tile); rows 64..255: W (k|q|v), 64 k-cols each, double-buffered
    __shared__ __align__(16) __bf16 Slds[2][256 * LDP];
    __shared__ __align__(16) __bf16 Vtl[64 * LDP];

    const int tid  = threadIdx.x;
    const int lane = tid & 63;
    const int wid  = tid >> 6;     // 0..15
    const int wm   = wid >> 2;     // 0..3 : 16-row group
    const int wn   = wid & 3;      // 0..3 : 48-col group
    const int mbase = blockIdx.x * 64;

    const int cl = lane & 15;          // fragment row/col lane index
    const int e0 = (lane >> 4) * 8;    // k-offset within 32-chunk
    const int r0 = (lane >> 4) * 4;    // C/D row group

    // A staging: thread -> (arow 0..63, acg 0..15), one float4 (4 fp32) per iter
    const int arow = tid >> 4, acg = tid & 15;
    const float* aptr = x + (size_t)(mbase + arow) * 1024 + acg * 4;

    float4 a0, a1;
    bf16x4 w0[3], w1[3];   // constant-indexed only (unrolled) -> stays in VGPRs

#define ISSUE(aset, wset, kb) { \
    aset = *reinterpret_cast<const float4*>(aptr + (kb)); \
    _Pragma("unroll") \
    for (int i_ = 0; i_ < 3; i_++) { \
        int c_ = i_ * 1024 + tid; \
        wset[i_] = *reinterpret_cast<const bf16x4*>(&wbf[(size_t)(c_ >> 4) * 1024 + (kb) + (c_ & 15) * 4]); \
    } }

#define COMMIT(aset, wset, bufi) { \
    bf16x4 av_; \
    av_[0] = (__bf16)aset.x; av_[1] = (__bf16)aset.y; av_[2] = (__bf16)aset.z; av_[3] = (__bf16)aset.w; \
    *reinterpret_cast<bf16x4*>(&Slds[bufi][arow * LDP + acg * 4]) = av_; \
    _Pragma("unroll") \
    for (int i_ = 0; i_ < 3; i_++) { \
        int c_ = i_ * 1024 + tid; \
        *reinterpret_cast<bf16x4*>(&Slds[bufi][(64 + (c_ >> 4)) * LDP + (c_ & 15) * 4]) = wset[i_]; \
    } }

    f32x4 acc[3];
    #pragma unroll
    for (int n = 0; n < 3; n++) acc[n] = (f32x4){0.f, 0.f, 0.f, 0.f};

    // prologue: s0 <- kb0 (commit immediately), s1 <- kb1 stays in flight
    ISSUE(a0, w0, 0);
    ISSUE(a1, w1, 64);
    COMMIT(a0, w0, 0);
    __syncthreads();

    #pragma unroll
    for (int j = 0; j < 16; j++) {
        const __bf16* buf = Slds[j & 1];
        #pragma unroll
        for (int kk = 0; kk < 2; kk++) {
            bf16x8 a = *reinterpret_cast<const bf16x8*>(&buf[(wm * 16 + cl) * LDP + kk * 32 + e0]);
            #pragma unroll
            for (int nf = 0; nf < 3; nf++) {
                bf16x8 b = *reinterpret_cast<const bf16x8*>(&buf[(64 + wn * 48 + nf * 16 + cl) * LDP + kk * 32 + e0]);
                acc[nf] = __builtin_amdgcn_mfma_f32_16x16x32_bf16(a, b, acc[nf], 0, 0, 0);
            }
        }
        if (j < 15) {
            // issue next-next K-block BEFORE committing (its vmcnt wait is counted past these)
            if (j < 14) {
                if (j & 1) { ISSUE(a1, w1, (j + 2) * 64); }
                else       { ISSUE(a0, w0, (j + 2) * 64); }
            }
            // commit the older in-flight set into the buffer read two iters ago
            if (j & 1) { COMMIT(a0, w0, 0); }
            else       { COMMIT(a1, w1, 1); }
        }
        __syncthreads();
    }
#undef ISSUE
#undef COMMIT

    // epilogue: k,q direct bf16 stores; v -> LDS transpose -> vtbuf
    #pragma unroll
    for (int nf = 0; nf < 3; nf++) {
        int c = wn * 48 + nf * 16 + cl;
        #pragma unroll
        for (int r = 0; r < 4; r++) {
            int mrel = wm * 16 + r0 + r;
            float v = acc[nf][r];
            if (c < 64)        kbuf[(size_t)(mbase + mrel) * 64 + c]         = (__bf16)v;
            else if (c < 128)  qbuf[(size_t)(mbase + mrel) * 64 + (c - 64)]  = (__bf16)v;
            else               Vtl[(c - 128) * LDP + mrel]                   = (__bf16)v;
        }
    }
    __syncthreads();
    {
        int b   = mbase >> 11;       // 2048 rows per batch
        int tof = mbase & 2047;
        int h   = tid >> 4;          // 0..63
        int seg = tid & 15;          // 4 bf16 each
        bf16x4 v4 = *reinterpret_cast<const bf16x4*>(&Vtl[h * LDP + seg * 4]);
        *reinterpret_cast<bf16x4*>(&vtbuf[(size_t)b * 64 * 2048 + (size_t)h * 2048 + tof + seg * 4]) = v4;
    }
}

// ---------------- Kernel 2: flash attention, split over the KV axis ----------------
// grid (32 q-tiles, nsplit, 8 batches), 256 threads = 4 waves; wave w owns 16 q rows.
// Split sp handles KV tiles [sp*tps, min((sp+1)*tps, qt+1)). nsplit==1 writes out
// directly; nsplit>1 writes unnormalized partials (acc, m, l) for the combine kernel.
// Padding mask is an OUTER PRODUCT mask[q]*mask[k]: column mask applied in-loop,
// row mask at the final write (fully-masked rows -> 0, matching nan_to_num).
__global__ __launch_bounds__(256) void attn_kernel(
    const __bf16* __restrict__ qbuf, const __bf16* __restrict__ kbuf,
    const __bf16* __restrict__ vtbuf, const int* __restrict__ mask,
    float* __restrict__ out, float* __restrict__ accpart, float* __restrict__ mlpart,
    int nsplit, int tps)
{
    __shared__ __align__(16) __bf16 Klds[64 * LDP];     // kv rows x 64 h
    __shared__ __align__(16) __bf16 Vlds[64 * LDP];     // h rows x 64 kv  (from vtbuf)
    __shared__ __align__(16) __bf16 Plds[4][16 * LDP];  // per-wave P tile: 16 q x 64 kv

    const int tid  = threadIdx.x;
    const int lane = tid & 63;
    const int w    = tid >> 6;
    const int qt   = blockIdx.x;
    const int sp   = blockIdx.y;
    const int b    = blockIdx.z;
    const int qbase = qt * 64 + w * 16;

    const int jbeg = sp * tps;
    const int jend = min((sp + 1) * tps, qt + 1);

    if (nsplit > 1 && jbeg >= jend) {
        // empty split: write zero partials (ws is poisoned; combine reads everything)
        float* ap = accpart + ((size_t)(b * nsplit + sp) * 2048 + qt * 64) * 64;
        for (int i = tid; i < 64 * 64; i += 256) ap[i] = 0.f;
        float* mp = mlpart + ((size_t)(b * nsplit + sp) * 2048 + qt * 64) * 2;
        for (int i = tid; i < 64; i += 256) { mp[2 * i] = -INFINITY; mp[2 * i + 1] = 0.f; }
        return;
    }

    const int cl = lane & 15;
    const int e0 = (lane >> 4) * 8;
    const int r0 = (lane >> 4) * 4;

    // Q fragments held in registers for the whole kernel
    bf16x8 aq[2];
    #pragma unroll
    for (int kk = 0; kk < 2; kk++)
        aq[kk] = *reinterpret_cast<const bf16x8*>(&qbuf[((size_t)b * 2048 + qbase + cl) * 64 + kk * 32 + e0]);

    float ms[4], ls[4];
    f32x4 acc[4];
    #pragma unroll
    for (int r = 0; r < 4; r++) { ms[r] = -INFINITY; ls[r] = 0.f; }
    #pragma unroll
    for (int hf = 0; hf < 4; hf++) acc[hf] = (f32x4){0.f, 0.f, 0.f, 0.f};

    const int srow = tid >> 3;   // 0..31
    const int scg  = tid & 7;

    for (int j = jbeg; j < jend; j++) {
        // stage K tile (kv-major) and Vt tile (h-major), 2 passes of 32 rows
        #pragma unroll
        for (int p = 0; p < 2; p++) {
            int rr = p * 32 + srow;
            *reinterpret_cast<bf16x8*>(&Klds[rr * LDP + scg * 8]) =
                *reinterpret_cast<const bf16x8*>(&kbuf[((size_t)b * 2048 + j * 64 + rr) * 64 + scg * 8]);
            *reinterpret_cast<bf16x8*>(&Vlds[rr * LDP + scg * 8]) =
                *reinterpret_cast<const bf16x8*>(&vtbuf[(size_t)b * 64 * 2048 + (size_t)rr * 2048 + j * 64 + scg * 8]);
        }
        __syncthreads();

        // S = Q K^T  (16 q x 64 kv per wave)
        f32x4 s[4];
        #pragma unroll
        for (int jf = 0; jf < 4; jf++) {
            f32x4 t = (f32x4){0.f, 0.f, 0.f, 0.f};
            #pragma unroll
            for (int kk = 0; kk < 2; kk++) {
                bf16x8 bk = *reinterpret_cast<const bf16x8*>(&Klds[(jf * 16 + cl) * LDP + kk * 32 + e0]);
                t = __builtin_amdgcn_mfma_f32_16x16x32_bf16(aq[kk], bk, t, 0, 0, 0);
            }
            s[jf] = t;
        }

        // scale + causal & padding (column) mask; per-row tile max
        float tmax[4] = {-INFINITY, -INFINITY, -INFINITY, -INFINITY};
        #pragma unroll
        for (int jf = 0; jf < 4; jf++) {
            int kv = j * 64 + jf * 16 + cl;
            int mk = mask[b * 2048 + kv];
            #pragma unroll
            for (int r = 0; r < 4; r++) {
                float sv = s[jf][r] * 0.125f;
                bool ok = (mk != 0) && (kv <= qbase + r0 + r);
                sv = ok ? sv : -INFINITY;
                s[jf][r] = sv;
                tmax[r] = fmaxf(tmax[r], sv);
            }
        }

        // online softmax: reduce across the 16 lanes holding this row's columns
        #pragma unroll
        for (int r = 0; r < 4; r++) {
            #pragma unroll
            for (int off = 1; off < 16; off <<= 1)
                tmax[r] = fmaxf(tmax[r], __shfl_xor(tmax[r], off));
            float mn = fmaxf(ms[r], tmax[r]);
            float alpha = (mn == -INFINITY) ? 1.0f : __expf(ms[r] - mn);
            float rs = 0.f;
            #pragma unroll
            for (int jf = 0; jf < 4; jf++) {
                float p = (mn == -INFINITY) ? 0.f : __expf(s[jf][r] - mn);
                s[jf][r] = p;
                rs += p;
            }
            #pragma unroll
            for (int off = 1; off < 16; off <<= 1)
                rs += __shfl_xor(rs, off);
            ls[r] = ls[r] * alpha + rs;
            ms[r] = mn;
            #pragma unroll
            for (int hf = 0; hf < 4; hf++) acc[hf][r] *= alpha;
        }

        // P -> wave-private LDS (to reach A-fragment layout), then O += P V
        #pragma unroll
        for (int jf = 0; jf < 4; jf++)
            #pragma unroll
            for (int r = 0; r < 4; r++)
                Plds[w][(r0 + r) * LDP + jf * 16 + cl] = (__bf16)s[jf][r];
        // same-wave LDS write->read: in-order DS pipe + compiler lgkmcnt; no barrier needed
        #pragma unroll
        for (int kk = 0; kk < 2; kk++) {
            bf16x8 ap = *reinterpret_cast<const bf16x8*>(&Plds[w][cl * LDP + kk * 32 + e0]);
            #pragma unroll
            for (int hf = 0; hf < 4; hf++) {
                bf16x8 bv = *reinterpret_cast<const bf16x8*>(&Vlds[(hf * 16 + cl) * LDP + kk * 32 + e0]);
                acc[hf] = __builtin_amdgcn_mfma_f32_16x16x32_bf16(ap, bv, acc[hf], 0, 0, 0);
            }
        }
        __syncthreads();  // before next tile overwrites K/V
    }

    if (nsplit == 1) {
        // direct epilogue: normalize; row mask (mask[q]==0 -> 0, matching nan_to_num)
        #pragma unroll
        for (int hf = 0; hf < 4; hf++)
            #pragma unroll
            for (int r = 0; r < 4; r++) {
                int qrow = qbase + r0 + r;
                int mq = mask[b * 2048 + qrow];
                float l = ls[r];
                float v = (l > 0.f && mq != 0) ? acc[hf][r] / l : 0.f;
                out[((size_t)b * 2048 + qrow) * 64 + hf * 16 + cl] = v;
            }
    } else {
        // partial epilogue: unnormalized acc + (m, l) per row
        #pragma unroll
        for (int hf = 0; hf < 4; hf++)
            #pragma unroll
            for (int r = 0; r < 4; r++) {
                int qrow = qbase + r0 + r;
                accpart[((size_t)(b * nsplit + sp) * 2048 + qrow) * 64 + hf * 16 + cl] = acc[hf][r];
            }
        if (cl == 0) {
            #pragma unroll
            for (int r = 0; r < 4; r++) {
                int qrow = qbase + r0 + r;
                mlpart[((size_t)(b * nsplit + sp) * 2048 + qrow) * 2 + 0] = ms[r];
                mlpart[((size_t)(b * nsplit + sp) * 2048 + qrow) * 2 + 1] = ls[r];
            }
        }
    }
}

// ---------------- Kernel 3: combine split partials ----------------
// templated split count -> static indexing (no scratch); thread per (q row, h).
template<int NS>
__global__ __launch_bounds__(256) void combine_kernel(
    const float* __restrict__ accpart, const float* __restrict__ mlpart,
    const int* __restrict__ mask, float* __restrict__ out)
{
    int idx = blockIdx.x * 256 + threadIdx.x;   // 0 .. 16384*64-1
    int qglob = idx >> 6;                        // = b*2048 + qrow
    int h = idx & 63;
    int b = qglob >> 11;
    int qrow = qglob & 2047;

    if (mask[qglob] == 0) { out[idx] = 0.f; return; }

    float m_s[NS], l_s[NS];
    float M = -INFINITY;
    #pragma unroll
    for (int s = 0; s < NS; s++) {
        size_t mo = ((size_t)(b * NS + s) * 2048 + qrow) * 2;
        m_s[s] = mlpart[mo];
        l_s[s] = mlpart[mo + 1];
        M = fmaxf(M, m_s[s]);
    }
    if (M == -INFINITY) { out[idx] = 0.f; return; }

    float L = 0.f, O = 0.f;
    #pragma unroll
    for (int s = 0; s < NS; s++) {
        float wgt = (m_s[s] == -INFINITY) ? 0.f : __expf(m_s[s] - M);
        L += l_s[s] * wgt;
        O += wgt * accpart[((size_t)(b * NS + s) * 2048 + qrow) * 64 + h];
    }
    out[idx] = (L > 0.f) ? O / L : 0.f;
}

extern "C" void kernel_launch(void* const* d_in, const int* in_sizes, int n_in,
                              void* d_out, int out_size, void* d_ws, size_t ws_size,
                              hipStream_t stream) {
    const float* x  = (const float*)d_in[0];
    const float* Wk = (const float*)d_in[1];
    const float* Wq = (const float*)d_in[2];
    const float* Wv = (const float*)d_in[3];
    const int* mask = (const int*)d_in[4];
    float* out = (float*)d_out;

    const size_t NTOK = 8 * 2048;          // 16384 rows
    __bf16* kbuf  = (__bf16*)d_ws;                    // [16384][64]
    __bf16* qbuf  = kbuf + NTOK * 64;                 // [16384][64]
    __bf16* vtbuf = qbuf + NTOK * 64;                 // [8][64][2048]
    __bf16* wbf   = vtbuf + (size_t)8 * 64 * 2048;    // [192][1024]
    const size_t base_bytes = NTOK * 64 * 2 * 2 + (size_t)8 * 64 * 2048 * 2
                            + (size_t)192 * 1024 * 2;  // 6,684,672

    // pick split count from available workspace (deterministic: ws_size is fixed)
    const size_t acc_per_split = NTOK * 64 * 4;       // 4 MiB
    const size_t ml_per_split  = NTOK * 2 * 4;        // 128 KiB
    int nsplit = 1;
    if (ws_size >= base_bytes + 4 * (acc_per_split + ml_per_split))      nsplit = 4;
    else if (ws_size >= base_bytes + 2 * (acc_per_split + ml_per_split)) nsplit = 2;

    float* accpart = (float*)((char*)d_ws + base_bytes);
    float* mlpart  = accpart + NTOK * 64 * nsplit;

    wconv_kernel<<<192, 256, 0, stream>>>(Wk, Wq, Wv, wbf);
    proj_kernel<<<256, 1024, 0, stream>>>(x, wbf, kbuf, qbuf, vtbuf);
    attn_kernel<<<dim3(32, nsplit, 8), 256, 0, stream>>>(
        qbuf, kbuf, vtbuf, mask, out, accpart, mlpart, nsplit, 32 / nsplit);
    if (nsplit == 4)
        combine_kernel<4><<<(16384 * 64) / 256, 256, 0, stream>>>(accpart, mlpart, mask, out);
    else if (nsplit == 2)
        combine_kernel<2><<<(16384 * 64) / 256, 256, 0, stream>>>(accpart, mlpart, mask, out);
}